// Round 5
// baseline (136.367 us; speedup 1.0000x reference)
//
#include <hip/hip_runtime.h>

#define HW   4096
#define HIMG 64
#define WIMG 64
#define CC   256
#define CR   32
#define B_   8

typedef __attribute__((ext_vector_type(8))) short bf16x8;
typedef __attribute__((ext_vector_type(4))) float f32x4;

__device__ inline unsigned short f2bf(float f) {
    union { float f; unsigned u; } v; v.f = f;
    return (unsigned short)((v.u + 0x8000u) >> 16);
}
__device__ inline float bf2f(unsigned short h) {
    union { unsigned u; float f; } v; v.u = ((unsigned)h) << 16; return v.f;
}
__device__ inline unsigned pack2(float a, float b) {
    return (unsigned)f2bf(a) | ((unsigned)f2bf(b) << 16);
}

// ---------------------------------------------------------------------------
// K1: weights -> bf16, concat [Wq;Wk;Wv] into Wb[320][256]; biases into bb.
// ---------------------------------------------------------------------------
__global__ __launch_bounds__(256) void wconv(
    const float* __restrict__ Wq, const float* __restrict__ bq,
    const float* __restrict__ Wk, const float* __restrict__ bk,
    const float* __restrict__ Wv, const float* __restrict__ bv,
    unsigned short* __restrict__ Wb, float* __restrict__ bb)
{
    const int o = blockIdx.x;   // 0..319
    const float* src; const float* bsrc; int orel;
    if (o < 32)      { src = Wq; bsrc = bq; orel = o;      }
    else if (o < 64) { src = Wk; bsrc = bk; orel = o - 32; }
    else             { src = Wv; bsrc = bv; orel = o - 64; }
    Wb[o * CC + threadIdx.x] = f2bf(src[orel * CC + threadIdx.x]);
    if (threadIdx.x == 0) bb[o] = bsrc[orel];
}

// ---------------------------------------------------------------------------
// K2: fused transpose+convert+GEMM. Block: M=320 x N=64 px, K=256 (4x64).
// x read from HBM exactly once; also emits xb = bf16(x) for apply's residual.
// ---------------------------------------------------------------------------
__global__ __launch_bounds__(256) void proj_gemm(
    const unsigned short* __restrict__ Wb, const float* __restrict__ bb,
    const float* __restrict__ x,
    float* __restrict__ q, float* __restrict__ k,
    unsigned short* __restrict__ vv, unsigned short* __restrict__ xb)
{
    __shared__ unsigned short As[320 * 72];
    __shared__ float          xt32[64 * 65];
    __shared__ unsigned short Bs[64 * 64];

    const int b   = blockIdx.y;
    const int hw0 = blockIdx.x * 64;
    const int t    = threadIdx.x;
    const int lane = t & 63, wv = t >> 6;
    const int m16  = lane & 15, quad = lane >> 4;

    f32x4 acc[5][4];
    #pragma unroll
    for (int i = 0; i < 5; ++i)
        #pragma unroll
        for (int n = 0; n < 4; ++n)
            acc[i][n] = (f32x4){0.f, 0.f, 0.f, 0.f};

    for (int kc = 0; kc < 4; ++kc) {
        const int k0 = kc * 64;
        if (kc) __syncthreads();            // protect As/xt32/Bs reuse

        // stage A: 320 rows x 64 k bf16 (L2-resident W)
        #pragma unroll
        for (int i = 0; i < 10; ++i) {
            int idx = t + 256 * i;          // 0..2559
            int row = idx >> 3, s8 = idx & 7;
            *(uint4*)&As[row * 72 + s8 * 8] =
                *(const uint4*)&Wb[row * CC + k0 + s8 * 8];
        }
        // stage x chunk fp32: 64 c x 64 px; also write bf16 copy to xb
        #pragma unroll
        for (int i = 0; i < 4; ++i) {
            int idx = t + 256 * i;          // 0..1023
            int c = idx >> 4, p4 = (idx & 15) * 4;
            size_t gidx = ((size_t)b * CC + k0 + c) * HW + hw0 + p4;
            float4 vx = *(const float4*)&x[gidx];
            *(float4*)&xt32[c * 65 + p4] = vx;
            ushort4 ub;
            ub.x = f2bf(vx.x); ub.y = f2bf(vx.y);
            ub.z = f2bf(vx.z); ub.w = f2bf(vx.w);
            *(ushort4*)&xb[gidx] = ub;
        }
        __syncthreads();

        // transpose+convert into Bs: thread -> px = lane, 16 channels
        {
            const int px = lane;
            const int c0 = wv * 16;
            float f[16];
            #pragma unroll
            for (int j = 0; j < 16; ++j)
                f[j] = xt32[(c0 + j) * 65 + px];   // 2-way aliasing: free
            uint4 w0, w1;
            w0.x = pack2(f[0],  f[1]);  w0.y = pack2(f[2],  f[3]);
            w0.z = pack2(f[4],  f[5]);  w0.w = pack2(f[6],  f[7]);
            w1.x = pack2(f[8],  f[9]);  w1.y = pack2(f[10], f[11]);
            w1.z = pack2(f[12], f[13]); w1.w = pack2(f[14], f[15]);
            const int lg0 = c0 >> 3, sw = px & 7;
            *(uint4*)&Bs[px * 64 + ((lg0     ^ sw) * 8)] = w0;
            *(uint4*)&Bs[px * 64 + (((lg0+1) ^ sw) * 8)] = w1;
        }
        __syncthreads();

        #pragma unroll
        for (int ks = 0; ks < 2; ++ks) {
            bf16x8 af[5], bf[4];
            #pragma unroll
            for (int i = 0; i < 5; ++i)
                af[i] = *(const bf16x8*)&As[((wv * 5 + i) * 16 + m16) * 72
                                            + ks * 32 + quad * 8];
            #pragma unroll
            for (int n = 0; n < 4; ++n) {
                int px = n * 16 + m16;
                int lg = ks * 4 + quad;
                bf[n] = *(const bf16x8*)&Bs[px * 64 + ((lg ^ (px & 7)) * 8)];
            }
            #pragma unroll
            for (int i = 0; i < 5; ++i)
                #pragma unroll
                for (int n = 0; n < 4; ++n)
                    acc[i][n] = __builtin_amdgcn_mfma_f32_16x16x32_bf16(
                        af[i], bf[n], acc[i][n], 0, 0, 0);
        }
    }

    // epilogue: D row = quad*4+reg, col = lane&15
    #pragma unroll
    for (int i = 0; i < 5; ++i) {
        const int ob = (wv * 5 + i) * 16;        // 0..304, wave-uniform
        #pragma unroll
        for (int r = 0; r < 4; ++r) {
            const int orow = quad * 4 + r;
            const float bias = bb[ob + orow];
            if (ob < 64) {                        // q or k, fp32
                float* dst = (ob < 32) ? q : k;
                int orel = (ob < 32) ? ob : ob - 32;
                size_t rowbase = ((size_t)b * CR + orel + orow) * HW;
                #pragma unroll
                for (int n = 0; n < 4; ++n)
                    dst[rowbase + hw0 + n * 16 + m16] = acc[i][n][r] + bias;
            } else {                              // v, bf16
                size_t rowbase = ((size_t)b * CC + (ob - 64) + orow) * HW;
                #pragma unroll
                for (int n = 0; n < 4; ++n)
                    vv[rowbase + hw0 + n * 16 + m16] = f2bf(acc[i][n][r] + bias);
            }
        }
    }
}

// ---------------------------------------------------------------------------
// K3: energies + softmax -> aw[b][hw][12]
// ---------------------------------------------------------------------------
__global__ __launch_bounds__(256) void attn_w(
    const float* __restrict__ q_, const float* __restrict__ k_,
    float* __restrict__ aw)
{
    __shared__ float qs[64][33];
    __shared__ float ks[3][64][33];
    __shared__ float es[64][9];
    const int h = blockIdx.x, b = blockIdx.y, t = threadIdx.x;

    #pragma unroll
    for (int i = 0; i < 2; ++i) {
        int idx = t + 256 * i, cr = idx >> 4, p4 = (idx & 15) * 4;
        float4 vq = *(const float4*)&q_[((size_t)b * CR + cr) * HW + h * WIMG + p4];
        qs[p4 + 0][cr] = vq.x; qs[p4 + 1][cr] = vq.y;
        qs[p4 + 2][cr] = vq.z; qs[p4 + 3][cr] = vq.w;
    }
    #pragma unroll
    for (int r = 0; r < 3; ++r) {
        int hh = h + r - 1;
        bool ok = (hh >= 0) && (hh < HIMG);
        #pragma unroll
        for (int i = 0; i < 2; ++i) {
            int idx = t + 256 * i, cr = idx >> 4, p4 = (idx & 15) * 4;
            float4 vk = make_float4(0.f, 0.f, 0.f, 0.f);
            if (ok)
                vk = *(const float4*)&k_[((size_t)b * CR + cr) * HW + hh * WIMG + p4];
            ks[r][p4 + 0][cr] = vk.x; ks[r][p4 + 1][cr] = vk.y;
            ks[r][p4 + 2][cr] = vk.z; ks[r][p4 + 3][cr] = vk.w;
        }
    }
    __syncthreads();

    for (int id = t; id < 576; id += 256) {
        int px = id / 9, kk = id - px * 9;
        int di = kk / 3, dj = kk - di * 3;
        int hh = h + di - 1, ww = px + dj - 1;
        float e = 0.f;
        if (hh >= 0 && hh < HIMG && ww >= 0 && ww < WIMG) {
            float s = 0.f;
            #pragma unroll
            for (int c = 0; c < CR; ++c) s = fmaf(qs[px][c], ks[di][ww][c], s);
            e = s;
        }
        es[px][kk] = e;
    }
    __syncthreads();

    if (t < 64) {
        float m = es[t][0];
        #pragma unroll
        for (int kk = 1; kk < 9; ++kk) m = fmaxf(m, es[t][kk]);
        float ex[9]; float ssum = 0.f;
        #pragma unroll
        for (int kk = 0; kk < 9; ++kk) { ex[kk] = __expf(es[t][kk] - m); ssum += ex[kk]; }
        float inv = 1.f / ssum;
        float* dst = &aw[((size_t)b * HW + h * WIMG + t) * 12];
        #pragma unroll
        for (int kk = 0; kk < 9; ++kk) dst[kk] = ex[kk] * inv;
    }
}

// ---------------------------------------------------------------------------
// K4: apply weights to v (bf16) + bf16 residual. Block = (h, 32-ch chunk, b).
// ---------------------------------------------------------------------------
__global__ __launch_bounds__(256) void apply(
    const unsigned short* __restrict__ xb, const unsigned short* __restrict__ vv,
    const float* __restrict__ aw, const float* __restrict__ gamma,
    float* __restrict__ out)
{
    __shared__ float vs[3][32][72];   // [row][ch][4 zero | 64 px | 4 zero]
    __shared__ float aws[64][12];
    const int h = blockIdx.x, cb = blockIdx.y, b = blockIdx.z, t = threadIdx.x;

    if (t < 192) {
        int px = t / 3, seg = t - px * 3;
        *(float4*)&aws[px][seg * 4] =
            *(const float4*)&aw[((size_t)b * HW + h * WIMG + px) * 12 + seg * 4];
    }
    #pragma unroll
    for (int i = 0; i < 6; ++i) {
        int idx = t + 256 * i;          // 0..1535
        int p4 = (idx & 15) * 4, c = (idx >> 4) & 31, r = idx >> 9;
        int hh = h + r - 1;
        float4 val = make_float4(0.f, 0.f, 0.f, 0.f);
        if (hh >= 0 && hh < HIMG) {
            ushort4 u = *(const ushort4*)&vv[((size_t)b * CC + cb * 32 + c) * HW
                                             + hh * WIMG + p4];
            val = make_float4(bf2f(u.x), bf2f(u.y), bf2f(u.z), bf2f(u.w));
        }
        *(float4*)&vs[r][c][4 + p4] = val;
    }
    if (t < 96) {
        int r = t >> 5, c = t & 31;
        float4 z = make_float4(0.f, 0.f, 0.f, 0.f);
        *(float4*)&vs[r][c][0]  = z;
        *(float4*)&vs[r][c][68] = z;
    }
    __syncthreads();

    const int px0 = (t & 15) * 4;
    const int cl  = t >> 4;
    float w[4][9];
    #pragma unroll
    for (int i = 0; i < 4; ++i)
        #pragma unroll
        for (int kk = 0; kk < 9; ++kk) w[i][kk] = aws[px0 + i][kk];
    const float g = gamma[0];

    #pragma unroll
    for (int ci = 0; ci < 2; ++ci) {
        int c = cl + 16 * ci;
        float a0 = 0.f, a1 = 0.f, a2 = 0.f, a3 = 0.f;
        #pragma unroll
        for (int r = 0; r < 3; ++r) {
            float4 ctr = *(float4*)&vs[r][c][4 + px0];
            float  lft = vs[r][c][3 + px0];
            float  rgt = vs[r][c][8 + px0];
            int r3 = r * 3;
            a0 = fmaf(w[0][r3], lft,   fmaf(w[0][r3+1], ctr.x, fmaf(w[0][r3+2], ctr.y, a0)));
            a1 = fmaf(w[1][r3], ctr.x, fmaf(w[1][r3+1], ctr.y, fmaf(w[1][r3+2], ctr.z, a1)));
            a2 = fmaf(w[2][r3], ctr.y, fmaf(w[2][r3+1], ctr.z, fmaf(w[2][r3+2], ctr.w, a2)));
            a3 = fmaf(w[3][r3], ctr.z, fmaf(w[3][r3+1], ctr.w, fmaf(w[3][r3+2], rgt,  a3)));
        }
        size_t base = ((size_t)b * CC + cb * 32 + c) * HW + h * WIMG + px0;
        ushort4 ux = *(const ushort4*)&xb[base];
        float4 o;
        o.x = fmaf(g, a0, bf2f(ux.x)); o.y = fmaf(g, a1, bf2f(ux.y));
        o.z = fmaf(g, a2, bf2f(ux.z)); o.w = fmaf(g, a3, bf2f(ux.w));
        *(float4*)&out[base] = o;
    }
}

extern "C" void kernel_launch(void* const* d_in, const int* in_sizes, int n_in,
                              void* d_out, int out_size, void* d_ws, size_t ws_size,
                              hipStream_t stream)
{
    const float* x     = (const float*)d_in[0];
    const float* Wq    = (const float*)d_in[1];
    const float* bq    = (const float*)d_in[2];
    const float* Wk    = (const float*)d_in[3];
    const float* bk    = (const float*)d_in[4];
    const float* Wv    = (const float*)d_in[5];
    const float* bv    = (const float*)d_in[6];
    const float* gamma = (const float*)d_in[7];
    float* out = (float*)d_out;

    float* q  = (float*)d_ws;                                         //  4.19 MB
    float* k  = q + (size_t)B_ * CR * HW;                             //  4.19 MB
    unsigned short* vv = (unsigned short*)(k + (size_t)B_ * CR * HW); // 16.78 MB
    unsigned short* xb = vv + (size_t)B_ * CC * HW;                   // 16.78 MB
    float* aw = (float*)(xb + (size_t)B_ * CC * HW);                  //  1.57 MB
    unsigned short* Wb = (unsigned short*)(aw + (size_t)B_ * HW * 12);//  160 KB
    float* bb = (float*)(Wb + 320 * CC);

    wconv<<<dim3(320), 256, 0, stream>>>(Wq, bq, Wk, bk, Wv, bv, Wb, bb);
    proj_gemm<<<dim3(HW / 64, B_), 256, 0, stream>>>(Wb, bb, x, q, k, vv, xb);
    attn_w<<<dim3(HIMG, B_), 256, 0, stream>>>(q, k, aw);
    apply<<<dim3(HIMG, CC / 32, B_), 256, 0, stream>>>(xb, vv, aw, gamma, out);
}